// Round 7
// baseline (117.581 us; speedup 1.0000x reference)
//
#include <hip/hip_runtime.h>
#include <hip/hip_bf16.h>
#include <stdint.h>
#include <stddef.h>

typedef __bf16 bf16_t;
typedef __attribute__((ext_vector_type(8))) __bf16 bf16x8;
typedef __attribute__((ext_vector_type(4))) float f32x4;

#define TOK 2048      // N*M tokens
#define DMODEL 1024
#define NHEAD 16

__device__ __forceinline__ void gload_lds16(const void* g, void* l) {
  __builtin_amdgcn_global_load_lds(
      (const __attribute__((address_space(1))) void*)g,
      (__attribute__((address_space(3))) void*)l, 16, 0, 0);
}

// ---------------- fp32 -> bf16 batched convert (X + weights) ----------------
struct CvtArgs {
  const float* src[7];
  bf16_t* dst[7];
  int n[7];
};

__global__ __launch_bounds__(256) void cvt_kernel(CvtArgs a) {
  int arr = blockIdx.y;
  int n = a.n[arr];
  int i = (blockIdx.x * 256 + threadIdx.x) * 8;
  if (i >= n) return;
  const float* s = a.src[arr];
  bf16_t* d = a.dst[arr];
  f32x4 x0 = *(const f32x4*)(s + i);
  f32x4 x1 = *(const f32x4*)(s + i + 4);
  bf16x8 o;
  o[0] = (bf16_t)x0[0]; o[1] = (bf16_t)x0[1]; o[2] = (bf16_t)x0[2]; o[3] = (bf16_t)x0[3];
  o[4] = (bf16_t)x1[0]; o[5] = (bf16_t)x1[1]; o[6] = (bf16_t)x1[2]; o[7] = (bf16_t)x1[3];
  *(bf16x8*)(d + i) = o;
}

// =============== GEMM: A-frags direct from global (L2), W via LDS ===============
// C[row][col] = sum_k A[row][k]*W[col][k] + bias[col]; M=2048, N=K=1024 per z.
// Block tile: BM = MI*32 rows x 64 cols, 4 waves as 2x2, wave-tile = MI*16 x 32.
// W: gload_lds 3-buf, both-sides XOR chunk swizzle, counted vmcnt.
// A: bf16, each wave loads its own fragments straight from global (no LDS).
// Per-step issue order [W(t+2) x2, A(t+2) x2*MI] => top-of-step vmcnt(2+2*MI)
// exactly leaves tile t+1's loads in flight (in-order retirement safe).
struct GArgs {
  const bf16_t* A[3];
  const bf16_t* W[3];
  const float* bias[3];
  void* C[3];
};

template <int MI, bool QKV3, typename CT>
__global__ __launch_bounds__(256, 3) void gemmA(GArgs g) {
  constexpr int K = DMODEL, N = DMODEL;
  constexpr int BM = MI * 32;
  constexpr int nt = K / 64;               // 16
  constexpr int APF = 2 * MI;              // A-frag loads per tile
  constexpr int INFLT = 2 + APF;           // one tile's loads (W2 + A)

  // XCD-local decode (blocks i -> XCD i%8): xcd owns contiguous bm strips.
  const int i = blockIdx.x;
  const int xcd = i & 7, slot = i >> 3;
  int z, bm, bn;
  if (QKV3) {                 // 768 blocks, MI=4: slot 0..95
    z = slot >> 5;
    const int s = slot & 31;
    bm = (xcd * 2 + (s >> 4)) * BM;        // 16 bm-tiles of 128
    bn = (s & 15) * 64;
  } else {                    // 512 blocks, MI=2: slot 0..63
    z = 0;
    bm = (xcd * 4 + (slot >> 4)) * BM;     // 32 bm-tiles of 64
    bn = (slot & 15) * 64;
  }

  const bf16_t* __restrict__ A = g.A[z];
  const bf16_t* __restrict__ W = g.W[z];
  const float* __restrict__ bias = g.bias[z];
  CT* __restrict__ C = (CT*)g.C[z];

  __shared__ alignas(16) bf16_t Bs[3][64 * 64];

  const int tid = threadIdx.x;
  const int wv = tid >> 6, lane = tid & 63;
  const int wr = (wv >> 1) * (MI * 16);    // wave row offset
  const int wc = (wv & 1) * 32;            // wave col offset
  const int lm = lane & 15, lch = lane >> 4;
  const int cr4 = (lane >> 4) * 4;

  // W staging coords (8 rows per gload, 2 gloads cover 64 rows)
  const int srow = wv * 8 + (lane >> 3);
  const int sc = (lane & 7) ^ (lane >> 3);
  const bf16_t* Wbase = W + (size_t)(bn + srow) * K + sc * 8;
  const int ldsoff0 = (wv * 8) * 64;
  const int ldsoff1 = (wv * 8 + 32) * 64;

  // A-frag per-lane base: row = bm + wr + ii*16 + lm, k = t*64 + kk*32 + lch*8
  const bf16_t* afrag = A + (size_t)(bm + wr + lm) * K + lch * 8;

  f32x4 acc[MI][2] = {};
  bf16x8 aE[APF], aO[APF];                 // even / odd tile A-frag sets

  auto loadA = [&](bf16x8* dst, int T) {
#pragma unroll
    for (int kk = 0; kk < 2; ++kk)
#pragma unroll
      for (int ii = 0; ii < MI; ++ii)
        dst[kk * MI + ii] =
            *(const bf16x8*)(afrag + (size_t)(ii * 16) * K + T * 64 + kk * 32);
  };

  // ---- prologue: [A0, W0] then [A1, W1] ----
  loadA(aE, 0);
  gload_lds16(Wbase, &Bs[0][ldsoff0]);
  gload_lds16(Wbase + (size_t)32 * K, &Bs[0][ldsoff1]);
  __builtin_amdgcn_sched_barrier(0);
  loadA(aO, 1);
  gload_lds16(Wbase + 64, &Bs[1][ldsoff0]);
  gload_lds16(Wbase + 64 + (size_t)32 * K, &Bs[1][ldsoff1]);
  __builtin_amdgcn_sched_barrier(0);

  auto step = [&](int T, bf16x8* ACUR) {
    // wait: tile T's A-regs + W-in-LDS done; tile T+1's INFLT loads stay out.
    if (T + 1 < nt) {
      asm volatile("s_waitcnt vmcnt(%0)" ::"i"(INFLT) : "memory");
    } else {
      asm volatile("s_waitcnt vmcnt(0)" ::: "memory");
    }
    __builtin_amdgcn_sched_barrier(0);
    __builtin_amdgcn_s_barrier();
    __builtin_amdgcn_sched_barrier(0);

    // issue W(T+2) into buf (T+2)%3 (freed by the barrier above)
    if (T + 2 < nt) {
      const bf16_t* wsrc = Wbase + (T + 2) * 64;
      bf16_t* wdst = &Bs[(T + 2) % 3][0];
      gload_lds16(wsrc, wdst + ldsoff0);
      gload_lds16(wsrc + (size_t)32 * K, wdst + ldsoff1);
    }
    __builtin_amdgcn_sched_barrier(0);

    // B-frags for tile T from LDS (XOR-swizzled chunks)
    bf16x8 fb[2][2];
#pragma unroll
    for (int kk = 0; kk < 2; ++kk)
#pragma unroll
      for (int jj = 0; jj < 2; ++jj) {
        const int rb = wc + jj * 16 + lm;
        fb[kk][jj] =
            *(const bf16x8*)&Bs[T % 3][rb * 64 + (((kk * 4 + lch) ^ (rb & 7)) * 8)];
      }
    asm volatile("s_waitcnt lgkmcnt(0)" ::: "memory");
    __builtin_amdgcn_sched_barrier(0);

    __builtin_amdgcn_s_setprio(1);
#pragma unroll
    for (int kk = 0; kk < 2; ++kk)
#pragma unroll
      for (int ii = 0; ii < MI; ++ii)
#pragma unroll
        for (int jj = 0; jj < 2; ++jj)
          acc[ii][jj] = __builtin_amdgcn_mfma_f32_16x16x32_bf16(
              ACUR[kk * MI + ii], fb[kk][jj], acc[ii][jj], 0, 0, 0);
    __builtin_amdgcn_s_setprio(0);
    __builtin_amdgcn_sched_barrier(0);

    // A(T+2) into the set just consumed (after MFMAs -> no WAR rename)
    if (T + 2 < nt) loadA(ACUR, T + 2);
    __builtin_amdgcn_sched_barrier(0);
  };

#pragma unroll 1
  for (int t2 = 0; t2 < nt / 2; ++t2) {
    step(t2 * 2, aE);
    step(t2 * 2 + 1, aO);
  }

  // ---- epilogue: bias + store ----
#pragma unroll
  for (int ii = 0; ii < MI; ++ii)
#pragma unroll
    for (int jj = 0; jj < 2; ++jj) {
      const int col = bn + wc + jj * 16 + lm;
      const float bvv = bias[col];
#pragma unroll
      for (int r = 0; r < 4; ++r) {
        const int row = bm + wr + ii * 16 + cr4 + r;
        C[(size_t)row * N + col] = (CT)(acc[ii][jj][r] + bvv);
      }
    }
}

// ---------------- per-(token,head) channel attention ----------------
__global__ __launch_bounds__(256) void attn_kernel(
    const bf16_t* __restrict__ q, const bf16_t* __restrict__ k,
    const bf16_t* __restrict__ v, bf16_t* __restrict__ ctx) {
  __shared__ float kv[4][64][2];
  const int wv = threadIdx.x >> 6, lane = threadIdx.x & 63;
  const int pair = blockIdx.x * 4 + wv;          // t*16 + h
  const size_t base = (size_t)pair * 64;
  float qd = (float)q[base + lane];
  float kd = (float)k[base + lane];
  float vd = (float)v[base + lane];
  kv[wv][lane][0] = kd;
  kv[wv][lane][1] = vd;
  __syncthreads();

  float kmax = kd, kmin = kd;
#pragma unroll
  for (int off = 32; off; off >>= 1) {
    kmax = fmaxf(kmax, __shfl_xor(kmax, off));
    kmin = fminf(kmin, __shfl_xor(kmin, off));
  }
  const float sc = 0.125f * 1.44269504088896341f;  // (1/sqrt(64)) * log2(e)
  float a = (float)qd * sc;
  float m = fmaxf(a * kmax, a * kmin);
  float sum = 0.f, accv = 0.f;
#pragma unroll 8
  for (int j = 0; j < 64; ++j) {
    float kj = kv[wv][j][0];
    float vj = kv[wv][j][1];
    float e = exp2f(fmaf(a, kj, -m));
    sum += e;
    accv = fmaf(e, vj, accv);
  }
  ctx[base + lane] = (bf16_t)(accv * __builtin_amdgcn_rcpf(sum));
}

// ---------------- launch ----------------
extern "C" void kernel_launch(void* const* d_in, const int* in_sizes, int n_in,
                              void* d_out, int out_size, void* d_ws, size_t ws_size,
                              hipStream_t stream) {
  const float* query = (const float*)d_in[0];
  const float* key   = (const float*)d_in[1];
  const float* value = (const float*)d_in[2];
  const float* Wq = (const float*)d_in[3];
  const float* bq = (const float*)d_in[4];
  const float* Wk = (const float*)d_in[5];
  const float* bk = (const float*)d_in[6];
  const float* Wv = (const float*)d_in[7];
  const float* bv = (const float*)d_in[8];
  const float* Wo = (const float*)d_in[9];
  const float* bo = (const float*)d_in[10];
  float* out = (float*)d_out;

  const size_t XE = (size_t)TOK * DMODEL;
  const size_t WE = (size_t)DMODEL * DMODEL;

  char* ws = (char*)d_ws;
  size_t off = 0;
  bf16_t* xb[3];
  for (int i = 0; i < 3; ++i) { xb[i] = (bf16_t*)(ws + off); off += XE * 2; }
  bf16_t* wb[4];
  for (int i = 0; i < 4; ++i) { wb[i] = (bf16_t*)(ws + off); off += WE * 2; }
  bf16_t* pb[3];   // projected q,k,v bf16
  for (int i = 0; i < 3; ++i) { pb[i] = (bf16_t*)(ws + off); off += XE * 2; }
  bf16_t* ctxb = (bf16_t*)(ws + off); off += XE * 2;

  // 1) convert X and weights to bf16
  CvtArgs ca;
  ca.src[0] = query; ca.src[1] = key; ca.src[2] = value;
  ca.src[3] = Wq; ca.src[4] = Wk; ca.src[5] = Wv; ca.src[6] = Wo;
  ca.dst[0] = xb[0]; ca.dst[1] = xb[1]; ca.dst[2] = xb[2];
  ca.dst[3] = wb[0]; ca.dst[4] = wb[1]; ca.dst[5] = wb[2]; ca.dst[6] = wb[3];
  ca.n[0] = ca.n[1] = ca.n[2] = (int)XE;
  ca.n[3] = ca.n[4] = ca.n[5] = ca.n[6] = (int)WE;
  cvt_kernel<<<dim3((unsigned)(XE / (256 * 8)), 7), 256, 0, stream>>>(ca);

  // 2) QKV projection: 768 blocks (128x64 tiles, 3 z's), one resident round
  GArgs g1;
  g1.A[0] = xb[0]; g1.A[1] = xb[1]; g1.A[2] = xb[2];
  g1.W[0] = wb[0]; g1.W[1] = wb[1]; g1.W[2] = wb[2];
  g1.bias[0] = bq; g1.bias[1] = bk; g1.bias[2] = bv;
  g1.C[0] = pb[0]; g1.C[1] = pb[1]; g1.C[2] = pb[2];
  gemmA<4, true, bf16_t><<<dim3(768), 256, 0, stream>>>(g1);

  // 3) per-(token,head) channel attention
  attn_kernel<<<dim3(TOK * NHEAD / 4), 256, 0, stream>>>(pb[0], pb[1], pb[2], ctxb);

  // 4) output projection -> fp32 out: 512 blocks (64x64 tiles)
  GArgs g2;
  g2.A[0] = ctxb; g2.W[0] = wb[3]; g2.bias[0] = bo; g2.C[0] = out;
  g2.A[1] = ctxb; g2.W[1] = wb[3]; g2.bias[1] = bo; g2.C[1] = out;
  g2.A[2] = ctxb; g2.W[2] = wb[3]; g2.bias[2] = bo; g2.C[2] = out;
  gemmA<2, false, float><<<dim3(512), 256, 0, stream>>>(g2);
}

// Round 8
// 79.106 us; speedup vs baseline: 1.4864x; 1.4864x over previous
//
#include <hip/hip_runtime.h>
#include <hip/hip_bf16.h>
#include <stdint.h>
#include <stddef.h>

typedef __bf16 bf16_t;
typedef __attribute__((ext_vector_type(8))) __bf16 bf16x8;
typedef __attribute__((ext_vector_type(4))) float f32x4;

#define TOK 2048      // N*M tokens
#define DMODEL 1024
#define NHEAD 16

__device__ __forceinline__ void gload_lds16(const void* g, void* l) {
  __builtin_amdgcn_global_load_lds(
      (const __attribute__((address_space(1))) void*)g,
      (__attribute__((address_space(3))) void*)l, 16, 0, 0);
}

// ---------------- fp32 -> bf16 batched convert (X + weights) ----------------
struct CvtArgs {
  const float* src[7];
  bf16_t* dst[7];
  int n[7];
};

__global__ __launch_bounds__(256) void cvt_kernel(CvtArgs a) {
  int arr = blockIdx.y;
  int n = a.n[arr];
  int i = (blockIdx.x * 256 + threadIdx.x) * 8;
  if (i >= n) return;
  const float* s = a.src[arr];
  bf16_t* d = a.dst[arr];
  f32x4 x0 = *(const f32x4*)(s + i);
  f32x4 x1 = *(const f32x4*)(s + i + 4);
  bf16x8 o;
  o[0] = (bf16_t)x0[0]; o[1] = (bf16_t)x0[1]; o[2] = (bf16_t)x0[2]; o[3] = (bf16_t)x0[3];
  o[4] = (bf16_t)x1[0]; o[5] = (bf16_t)x1[1]; o[6] = (bf16_t)x1[2]; o[7] = (bf16_t)x1[3];
  *(bf16x8*)(d + i) = o;
}

// =============== m97-analog GEMM: both operands via gload_lds, 2-buf ===============
// C[row][col] = sum_k A[row][k]*W[col][k] + bias[col]; per z: M=2048, N=K=1024.
// Tile BM x 64 (BM = MI*32), 4 waves 2x2, wave tile = MI*16 x 32.
// Staging: 16B global_load_lds, linear LDS, XOR chunk swizzle on BOTH the
// per-lane global source and the ds_read offsets (round-7-verified: 0 conflicts).
// Pipeline: 2 LDS buffers; per step: __syncthreads (drains vmcnt) -> issue
// tile T+1 -> ds_read frags of T -> MFMA. Post-barrier prefetch hides L2/L3
// latency under the ~1000cyc step body.
struct GArgs {
  const bf16_t* A[3];
  const bf16_t* W[3];
  const float* bias[3];
  void* C[3];
};

template <int MI, bool QKV3, typename CT>
__global__ __launch_bounds__(256, 3) void gemmL(GArgs g) {
  constexpr int K = DMODEL, N = DMODEL;
  constexpr int BM = MI * 32;          // 128 (QKV) / 64 (out-proj)
  constexpr int nt = K / 64;           // 16
  constexpr int AG = BM / 32;          // A gloads per wave per tile (4 / 2)

  // XCD-local decode (hw: blockIdx round-robins XCDs -> i&7 is the XCD)
  const int i = blockIdx.x;
  const int xcd = i & 7, slot = i >> 3;
  int z, bm, bn;
  if (QKV3) {                  // 768 blocks: 16 bm-strips x 16 bn x 3 z
    z = slot >> 5;
    const int s = slot & 31;
    bm = (xcd * 2 + (s >> 4)) * BM;
    bn = (s & 15) * 64;
  } else {                     // 512 blocks: 32 bm x 16 bn
    z = 0;
    bm = (xcd * 4 + (slot >> 4)) * BM;
    bn = (slot & 15) * 64;
  }

  const bf16_t* __restrict__ A = g.A[z];
  const bf16_t* __restrict__ W = g.W[z];
  const float* __restrict__ bias = g.bias[z];
  CT* __restrict__ C = (CT*)g.C[z];

  __shared__ alignas(16) bf16_t As[2][BM * 64];
  __shared__ alignas(16) bf16_t Bs[2][64 * 64];

  const int tid = threadIdx.x;
  const int wv = tid >> 6, lane = tid & 63;
  const int wr = (wv >> 1) * (MI * 16);
  const int wc = (wv & 1) * 32;
  const int lm = lane & 15, lch = lane >> 4;
  const int cr4 = (lane >> 4) * 4;

  // staging coords: one gload covers 8 rows (8 lanes x 16B per row);
  // source chunk pre-XORed so LDS[r][c] = G[r][c ^ (r&7)]
  const int sr8 = lane >> 3;
  const int sc = (lane & 7) ^ sr8;
  const bf16_t* Asrc = A + (size_t)(bm + wv * (8 * AG) + sr8) * K + sc * 8;
  const bf16_t* Wsrc = W + (size_t)(bn + wv * 8 + sr8) * K + sc * 8;

  f32x4 acc[MI][2] = {};

#define STAGE(T)                                                               \
  {                                                                            \
    const int _b = (T) & 1;                                                    \
    _Pragma("unroll") for (int j = 0; j < AG; ++j)                             \
        gload_lds16(Asrc + (size_t)(j * 8) * K + (T) * 64,                     \
                    &As[_b][(wv * 8 * AG + j * 8) * 64]);                      \
    gload_lds16(Wsrc + (T) * 64, &Bs[_b][(wv * 8) * 64]);                      \
    gload_lds16(Wsrc + (size_t)32 * K + (T) * 64, &Bs[_b][(wv * 8 + 32) * 64]);\
  }

  STAGE(0);

#pragma unroll 1
  for (int T = 0; T < nt; ++T) {
    __syncthreads();               // vmcnt(0)+lgkm(0)+barrier: tile T landed,
                                   // buf (T+1)&1 free (all waves past its reads)
    if (T + 1 < nt) STAGE(T + 1);
    __builtin_amdgcn_sched_barrier(0);

    const int b = T & 1;
#pragma unroll
    for (int kk = 0; kk < 2; ++kk) {
      bf16x8 fa[MI], fb[2];
#pragma unroll
      for (int ii = 0; ii < MI; ++ii) {
        const int r = wr + ii * 16 + lm;
        fa[ii] = *(const bf16x8*)&As[b][r * 64 + (((kk * 4 + lch) ^ (r & 7)) * 8)];
      }
#pragma unroll
      for (int jj = 0; jj < 2; ++jj) {
        const int r = wc + jj * 16 + lm;
        fb[jj] = *(const bf16x8*)&Bs[b][r * 64 + (((kk * 4 + lch) ^ (r & 7)) * 8)];
      }
#pragma unroll
      for (int ii = 0; ii < MI; ++ii)
#pragma unroll
        for (int jj = 0; jj < 2; ++jj)
          acc[ii][jj] = __builtin_amdgcn_mfma_f32_16x16x32_bf16(
              fa[ii], fb[jj], acc[ii][jj], 0, 0, 0);
    }
  }
#undef STAGE

  // ---- epilogue: bias + store ----
#pragma unroll
  for (int ii = 0; ii < MI; ++ii)
#pragma unroll
    for (int jj = 0; jj < 2; ++jj) {
      const int col = bn + wc + jj * 16 + lm;
      const float bvv = bias[col];
#pragma unroll
      for (int r = 0; r < 4; ++r) {
        const int row = bm + wr + ii * 16 + cr4 + r;
        C[(size_t)row * N + col] = (CT)(acc[ii][jj][r] + bvv);
      }
    }
}

// ---------------- per-(token,head) channel attention ----------------
__global__ __launch_bounds__(256) void attn_kernel(
    const bf16_t* __restrict__ q, const bf16_t* __restrict__ k,
    const bf16_t* __restrict__ v, bf16_t* __restrict__ ctx) {
  __shared__ float kv[4][64][2];
  const int wv = threadIdx.x >> 6, lane = threadIdx.x & 63;
  const int pair = blockIdx.x * 4 + wv;          // t*16 + h
  const size_t base = (size_t)pair * 64;
  float qd = (float)q[base + lane];
  float kd = (float)k[base + lane];
  float vd = (float)v[base + lane];
  kv[wv][lane][0] = kd;
  kv[wv][lane][1] = vd;
  __syncthreads();

  float kmax = kd, kmin = kd;
#pragma unroll
  for (int off = 32; off; off >>= 1) {
    kmax = fmaxf(kmax, __shfl_xor(kmax, off));
    kmin = fminf(kmin, __shfl_xor(kmin, off));
  }
  const float sc = 0.125f * 1.44269504088896341f;  // (1/sqrt(64)) * log2(e)
  float a = (float)qd * sc;
  float m = fmaxf(a * kmax, a * kmin);
  float sum = 0.f, accv = 0.f;
#pragma unroll 8
  for (int j = 0; j < 64; ++j) {
    float kj = kv[wv][j][0];
    float vj = kv[wv][j][1];
    float e = exp2f(fmaf(a, kj, -m));
    sum += e;
    accv = fmaf(e, vj, accv);
  }
  ctx[base + lane] = (bf16_t)(accv * __builtin_amdgcn_rcpf(sum));
}

// ---------------- launch ----------------
extern "C" void kernel_launch(void* const* d_in, const int* in_sizes, int n_in,
                              void* d_out, int out_size, void* d_ws, size_t ws_size,
                              hipStream_t stream) {
  const float* query = (const float*)d_in[0];
  const float* key   = (const float*)d_in[1];
  const float* value = (const float*)d_in[2];
  const float* Wq = (const float*)d_in[3];
  const float* bq = (const float*)d_in[4];
  const float* Wk = (const float*)d_in[5];
  const float* bk = (const float*)d_in[6];
  const float* Wv = (const float*)d_in[7];
  const float* bv = (const float*)d_in[8];
  const float* Wo = (const float*)d_in[9];
  const float* bo = (const float*)d_in[10];
  float* out = (float*)d_out;

  const size_t XE = (size_t)TOK * DMODEL;
  const size_t WE = (size_t)DMODEL * DMODEL;

  char* ws = (char*)d_ws;
  size_t off = 0;
  bf16_t* xb[3];
  for (int i = 0; i < 3; ++i) { xb[i] = (bf16_t*)(ws + off); off += XE * 2; }
  bf16_t* wb[4];
  for (int i = 0; i < 4; ++i) { wb[i] = (bf16_t*)(ws + off); off += WE * 2; }
  bf16_t* pb[3];   // projected q,k,v bf16
  for (int i = 0; i < 3; ++i) { pb[i] = (bf16_t*)(ws + off); off += XE * 2; }
  bf16_t* ctxb = (bf16_t*)(ws + off); off += XE * 2;

  // 1) convert X and weights to bf16
  CvtArgs ca;
  ca.src[0] = query; ca.src[1] = key; ca.src[2] = value;
  ca.src[3] = Wq; ca.src[4] = Wk; ca.src[5] = Wv; ca.src[6] = Wo;
  ca.dst[0] = xb[0]; ca.dst[1] = xb[1]; ca.dst[2] = xb[2];
  ca.dst[3] = wb[0]; ca.dst[4] = wb[1]; ca.dst[5] = wb[2]; ca.dst[6] = wb[3];
  ca.n[0] = ca.n[1] = ca.n[2] = (int)XE;
  ca.n[3] = ca.n[4] = ca.n[5] = ca.n[6] = (int)WE;
  cvt_kernel<<<dim3((unsigned)(XE / (256 * 8)), 7), 256, 0, stream>>>(ca);

  // 2) QKV projection: 768 blocks (128x64 tiles x 16 bn x 3 z), 3 blocks/CU
  GArgs g1;
  g1.A[0] = xb[0]; g1.A[1] = xb[1]; g1.A[2] = xb[2];
  g1.W[0] = wb[0]; g1.W[1] = wb[1]; g1.W[2] = wb[2];
  g1.bias[0] = bq; g1.bias[1] = bk; g1.bias[2] = bv;
  g1.C[0] = pb[0]; g1.C[1] = pb[1]; g1.C[2] = pb[2];
  gemmL<4, true, bf16_t><<<dim3(768), 256, 0, stream>>>(g1);

  // 3) per-(token,head) channel attention
  attn_kernel<<<dim3(TOK * NHEAD / 4), 256, 0, stream>>>(pb[0], pb[1], pb[2], ctxb);

  // 4) output projection -> fp32 out: 512 blocks (64x64 tiles), 2 blocks/CU
  GArgs g2;
  g2.A[0] = ctxb; g2.W[0] = wb[3]; g2.bias[0] = bo; g2.C[0] = out;
  g2.A[1] = ctxb; g2.W[1] = wb[3]; g2.bias[1] = bo; g2.C[1] = out;
  g2.A[2] = ctxb; g2.W[2] = wb[3]; g2.bias[2] = bo; g2.C[2] = out;
  gemmL<2, false, float><<<dim3(512), 256, 0, stream>>>(g2);
}